// Round 13
// baseline (4265.660 us; speedup 1.0000x reference)
//
#include <hip/hip_runtime.h>
#include <hip/hip_bf16.h>
#include <math.h>

#define N 8192
#define BATCH 2
#define NROWS (BATCH*N)

typedef float v2f __attribute__((ext_vector_type(2)));

static __device__ __forceinline__ float fsubr(float a, float b){ return __fadd_rn(a, -b); }
static __device__ __forceinline__ unsigned okey(float f){
  unsigned u = __float_as_uint(f);
  return (u & 0x80000000u) ? ~u : (u | 0x80000000u);
}

// ---------------- aux: transpose xyz + |p|^2 + masked-coord image + global max (okey atomicMax)
__global__ void aux_kernel(const float* __restrict__ xyz, float* __restrict__ xs, float* __restrict__ ys,
                           float* __restrict__ zs, float* __restrict__ sq, float4* __restrict__ mxyz,
                           unsigned* __restrict__ farkey){
  __shared__ unsigned lm[4];
  const int t = threadIdx.x;
  int i = blockIdx.x*256 + t;
  float m = -1e30f;
  if (i < NROWS){
    float x = xyz[i*3+0], y = xyz[i*3+1], z = xyz[i*3+2];
    xs[i]=x; ys[i]=y; zs[i]=z;
    sq[i] = __fadd_rn(__fadd_rn(__fmul_rn(x,x),__fmul_rn(y,y)),__fmul_rn(z,z));
    mxyz[i] = make_float4(x, y, z, 0.0f);
    m = fmaxf(fmaxf(x, y), z);
  }
  #pragma unroll
  for (int off = 32; off; off >>= 1) m = fmaxf(m, __shfl_down(m, off));
  if ((t & 63) == 0) lm[t >> 6] = okey(m);
  __syncthreads();
  if (t == 0){
    unsigned k = lm[0];
    k = k > lm[1] ? k : lm[1];
    k = k > lm[2] ? k : lm[2];
    k = k > lm[3] ? k : lm[3];
    atomicMax(farkey, k);
  }
}

// ---------------- Q = xyz @ w1[:3] + feat @ w1[3:]  (per global row, 128 cols)
__global__ __launch_bounds__(128) void q_kernel(const float* __restrict__ xyz, const float* __restrict__ feat,
                                                const float* __restrict__ w1, float* __restrict__ Q){
  __shared__ float sx[16][3];
  __shared__ float sf[16][64];
  const int t = threadIdx.x;
  const int row0 = blockIdx.x * 16;
  for (int j = t; j < 1024; j += 128) sf[j>>6][j&63] = feat[(size_t)row0*64 + j];
  if (t < 48) sx[t/3][t%3] = xyz[(size_t)row0*3 + t];
  __syncthreads();
  float acc[16];
  #pragma unroll
  for (int r = 0; r < 16; ++r) acc[r] = 0.0f;
  for (int c = 0; c < 3; ++c){
    float wv = w1[c*128 + t];
    #pragma unroll
    for (int r = 0; r < 16; ++r) acc[r] = fmaf(sx[r][c], wv, acc[r]);
  }
  for (int c = 0; c < 64; ++c){
    float wv = w1[(3+c)*128 + t];
    #pragma unroll
    for (int r = 0; r < 16; ++r) acc[r] = fmaf(sf[r][c], wv, acc[r]);
  }
  #pragma unroll
  for (int r = 0; r < 16; ++r) Q[(size_t)(row0+r)*128 + t] = acc[r];
}

// ---------------- KNN: per row, exact 65 smallest (d2, idx), drop rank0 (self), store 64 cand
// R13: threshold-select. Any T with |{d2 < T}| in [65, 1536] admits the exact top-65
// (strict < keeps all ties of the 65th value inside the set); collected candidates are
// exact-ranked by (okey(d2), idx) as before -> byte-identical output. T found by
// register-count bisection (16 compares + DPP wave-sum + 1 barrier per round), warm-
// started from the previous row's accepted T. Deletes per row: 16384 hist atomics,
// 16 fk LDS stores, 2 scan phases. LDS 49.6 KB -> ~12.5 KB.
#define KNN_WIN 1536
#define DPPSUMU(CTRL) { int o = __builtin_amdgcn_update_dpp(0, (int)c, (CTRL), 0xf, 0xf, true); c += (unsigned)o; }
__global__ __launch_bounds__(512, 2) void knn_kernel(const float* __restrict__ xs, const float* __restrict__ ys,
                                                     const float* __restrict__ zs, const float* __restrict__ sq,
                                                     int* __restrict__ cand){
#pragma clang fp contract(off)
  __shared__ unsigned long long win[KNN_WIN];
  __shared__ unsigned wcnt[2][8];
  __shared__ int scal[2];
  const int t = threadIdx.x;
  const int base_row = blockIdx.x * 32;           // 512 blocks x 32 rows
  const int b = base_row >> 13;
  const int n0 = base_row & (N-1);
  const int pbase = b * N;
  v2f px[8], py[8], pz[8], ps[8];
  #pragma unroll
  for (int k = 0; k < 8; ++k){
    int i0 = t + (2*k)*512, i1 = t + (2*k+1)*512;
    px[k].x = xs[pbase+i0]; px[k].y = xs[pbase+i1];
    py[k].x = ys[pbase+i0]; py[k].y = ys[pbase+i1];
    pz[k].x = zs[pbase+i0]; pz[k].y = zs[pbase+i1];
    ps[k].x = sq[pbase+i0]; ps[k].y = sq[pbase+i1];
  }
  float T = 0.3f;                                 // warm-start carries across rows
  for (int r = 0; r < 32; ++r){
    const int n = n0 + r;
    const float qx = xs[pbase+n], qy = ys[pbase+n], qz = zs[pbase+n], qs = sq[pbase+n];
    v2f d2[8];
    #pragma unroll
    for (int k = 0; k < 8; ++k){
      v2f dot = px[k]*qx + py[k]*qy + pz[k]*qz;   // ((mul+mul)+mul), rn, contract off
      d2[k]   = (qs + ps[k]) - 2.0f*dot;          // 2*dot exact; one rounding on sub
    }
    // ---- bisection for threshold T with count in [65, KNN_WIN] ----
    float lo = 0.0f, hi = 0.0f;
    bool hiset = false;
    for (int itb = 0; itb < 32; ++itb){
      unsigned c = 0;
      #pragma unroll
      for (int k = 0; k < 8; ++k){
        c += (d2[k].x < T) ? 1u : 0u;
        c += (d2[k].y < T) ? 1u : 0u;
      }
      DPPSUMU(0x111) DPPSUMU(0x112) DPPSUMU(0x114) DPPSUMU(0x118)
      DPPSUMU(0x142) DPPSUMU(0x143)               // lane63: wave sum
      if ((t & 63) == 63) wcnt[itb & 1][t >> 6] = c;
      if (t == 0) scal[0] = 0;
      __syncthreads();
      const unsigned* wc = wcnt[itb & 1];
      unsigned cnt = wc[0]+wc[1]+wc[2]+wc[3]+wc[4]+wc[5]+wc[6]+wc[7];
      if (cnt >= 65u && cnt <= (unsigned)KNN_WIN) break;     // uniform
      if (cnt < 65u){ lo = T; T = hiset ? 0.5f*(lo+hi) : T*4.0f; }
      else          { hi = T; hiset = true; T = 0.5f*(lo+hi); }
    }
    // ---- collect candidates (< T), exact-rank, emit top 1..64 ----
    #pragma unroll
    for (int k = 0; k < 8; ++k){
      if (d2[k].x < T){
        int p = atomicAdd(&scal[0], 1);
        if (p < KNN_WIN) win[p] = ((unsigned long long)okey(d2[k].x) << 32) | (unsigned)(t + (2*k)*512);
      }
      if (d2[k].y < T){
        int p = atomicAdd(&scal[0], 1);
        if (p < KNN_WIN) win[p] = ((unsigned long long)okey(d2[k].y) << 32) | (unsigned)(t + (2*k+1)*512);
      }
    }
    __syncthreads();
    int m = scal[0]; if (m > KNN_WIN) m = KNN_WIN;
    for (int e = t; e < m; e += 512){
      unsigned long long me = win[e];
      int rk = 0;
      for (int j2 = 0; j2 < m; ++j2) rk += (win[j2] < me) ? 1 : 0;
      if (rk >= 1 && rk < 65) cand[(size_t)(pbase + n)*64 + (rk-1)] = (int)(me & 0xFFFFFFFFull);
    }
    __syncthreads();
  }
}

// ---------------- scores + top16 + covariance/eigen curvature + feat_var  (one wave per row)
__global__ __launch_bounds__(256) void score_kernel(const float* __restrict__ xyz, const float* __restrict__ feat,
                                                    const float* __restrict__ Q, const float* __restrict__ b1,
                                                    const float* __restrict__ w2, const float* __restrict__ b2,
                                                    const int* __restrict__ cand,
                                                    float* __restrict__ curv, float* __restrict__ fv){
  __shared__ float4 sb14[32], sw24[32];
  __shared__ int ssel[4][16];
  __shared__ float sdx[4][16], sdy[4][16], sdz[4][16], snrm[4][16];
  const int t = threadIdx.x;
  if (t < 32) sb14[t] = ((const float4*)b1)[t];
  else if (t < 64) sw24[t-32] = ((const float4*)w2)[t-32];
  __syncthreads();
  const int w = t >> 6, lane = t & 63;
  const int row = blockIdx.x*4 + w;               // global row
  const int b = row >> 13;
  const int pbase = b * N;
  const int n = row & (N-1);
  const int ck = cand[(size_t)row*64 + lane];
  const float4* Qn4 = (const float4*)(Q + (size_t)row * 128);
  const float4* Qc4 = (const float4*)(Q + (size_t)(pbase + ck) * 128);
  const float ks = 0.70710678118654752440f;
  float acc = 0.0f;
  for (int c = 0; c < 32; ++c){
    float4 qc = Qc4[c], qn = Qn4[c], bb = sb14[c], ww = sw24[c];
    float p0 = (qc.x - qn.x) + bb.x;
    float g0 = 0.5f * p0 * (1.0f + erff(p0 * ks));
    acc += g0 * ww.x;
    float p1 = (qc.y - qn.y) + bb.y;
    float g1 = 0.5f * p1 * (1.0f + erff(p1 * ks));
    acc += g1 * ww.y;
    float p2 = (qc.z - qn.z) + bb.z;
    float g2 = 0.5f * p2 * (1.0f + erff(p2 * ks));
    acc += g2 * ww.z;
    float p3 = (qc.w - qn.w) + bb.w;
    float g3 = 0.5f * p3 * (1.0f + erff(p3 * ks));
    acc += g3 * ww.w;
  }
  float score = acc + b2[0];
  unsigned key = okey(score);
  int rk = 0;
  for (int j = 0; j < 64; ++j){
    unsigned kj = (unsigned)__shfl((int)key, j);
    rk += (kj > key || (kj == key && j < lane)) ? 1 : 0;
  }
  float cx = xyz[(size_t)(pbase+ck)*3+0], cy = xyz[(size_t)(pbase+ck)*3+1], cz = xyz[(size_t)(pbase+ck)*3+2];
  float qxv = xyz[(size_t)(pbase+n)*3+0], qyv = xyz[(size_t)(pbase+n)*3+1], qzv = xyz[(size_t)(pbase+n)*3+2];
  if (rk < 16){
    ssel[w][rk] = ck;
    sdx[w][rk] = fsubr(cx, qxv);
    sdy[w][rk] = fsubr(cy, qyv);
    sdz[w][rk] = fsubr(cz, qzv);
  }
  __syncthreads();
  if (lane < 16){
    int si = ssel[w][lane];
    const float4* fc4 = (const float4*)(feat + (size_t)(pbase+si)*64);
    const float4* fn4 = (const float4*)(feat + (size_t)(pbase+n)*64);
    double s = 0.0;
    for (int c = 0; c < 16; ++c){
      float4 a = fc4[c], bq = fn4[c];
      float d0 = fsubr(a.x, bq.x); s += (double)d0 * (double)d0;
      float d1 = fsubr(a.y, bq.y); s += (double)d1 * (double)d1;
      float d2 = fsubr(a.z, bq.z); s += (double)d2 * (double)d2;
      float d3 = fsubr(a.w, bq.w); s += (double)d3 * (double)d3;
    }
    snrm[w][lane] = sqrtf((float)s);
  }
  __syncthreads();
  if (lane == 0){
    double cxx=0, cxy=0, cxz=0, cyy=0, cyz=0, czz=0;
    for (int k2 = 0; k2 < 16; ++k2){
      double dx = (double)sdx[w][k2], dy = (double)sdy[w][k2], dz = (double)sdz[w][k2];
      cxx += dx*dx; cxy += dx*dy; cxz += dx*dz; cyy += dy*dy; cyz += dy*dz; czz += dz*dz;
    }
    float fxx = (float)(cxx/16.0), fxy = (float)(cxy/16.0), fxz = (float)(cxz/16.0);
    float fyy = (float)(cyy/16.0), fyz = (float)(cyz/16.0), fzz = (float)(czz/16.0);
    double a = fxx, bbv = fyy, c = fzz, d = fxy, e = fyz, f = fxz;
    double p1 = d*d + f*f + e*e;
    double e0, e1, e2v;
    if (p1 == 0.0){ e0 = a; e1 = bbv; e2v = c; }
    else {
      double q = (a + bbv + c) / 3.0;
      double aa = a - q, bq = bbv - q, cc = c - q;
      double p2 = aa*aa + bq*bq + cc*cc + 2.0*p1;
      double p = sqrt(p2 / 6.0);
      double inv = 1.0 / p;
      double bxx = aa*inv, byy = bq*inv, bzz = cc*inv, bxy = d*inv, bxz = f*inv, byz = e*inv;
      double detB = bxx*(byy*bzz - byz*byz) - bxy*(bxy*bzz - byz*bxz) + bxz*(bxy*byz - byy*bxz);
      double rr = 0.5 * detB;
      rr = fmin(1.0, fmax(-1.0, rr));
      double phi = acos(rr) / 3.0;
      e0 = q + 2.0*p*cos(phi);
      e2v = q + 2.0*p*cos(phi + 2.0943951023931953);
      e1 = 3.0*q - e0 - e2v;
    }
    double s0 = fabs(e0), s1 = fabs(e1), s2d = fabs(e2v), tt;
    if (s0 < s1){ tt=s0; s0=s1; s1=tt; }
    if (s1 < s2d){ tt=s1; s1=s2d; s2d=tt; }
    if (s0 < s1){ tt=s0; s0=s1; s1=tt; }
    float sv0 = (float)s0, sv1 = (float)s1, sv2 = (float)s2d;
    float l2f = __fmul_rn(sv0,sv0), l1f = __fmul_rn(sv1,sv1), l0f = __fmul_rn(sv2,sv2);
    float den = __fadd_rn(__fadd_rn(__fadd_rn(l0f, l1f), l2f), 1e-8f);
    curv[row] = l0f / den;
    double fs = 0.0;
    for (int k2 = 0; k2 < 16; ++k2) fs += (double)snrm[w][k2];
    fv[row] = (float)(fs / 16.0);
  }
}

// ---------------- merged: per-batch znorm + importance (regs) -> top-1024 + masked-coord scatter
static __device__ __forceinline__ double blk_sum(double v, double* lds, int t){
  for (int off = 32; off; off >>= 1) v += __shfl_down(v, off);
  int w = t >> 6, lane = t & 63;
  if (lane == 0) lds[w] = v;
  __syncthreads();
  double r = (t < 16) ? lds[t] : 0.0;
  if (t < 64){ for (int off = 8; off; off >>= 1) r += __shfl_down(r, off); }
  if (t == 0) lds[0] = r;
  __syncthreads();
  double out = lds[0];
  __syncthreads();
  return out;
}

#define TBINBASE 0x3E00
__global__ __launch_bounds__(1024) void stats_topk_kernel(const float* __restrict__ curv, const float* __restrict__ fv,
                                                          int* __restrict__ merged, float4* __restrict__ mxyz,
                                                          const unsigned* __restrict__ farkey){
  __shared__ unsigned dk[N];
  __shared__ unsigned hist[2048];
  __shared__ unsigned long long win[2048];
  __shared__ int scal[8];
  __shared__ double lds[16];
  const int t = threadIdx.x;
  const int b = blockIdx.x;
  const int base = b * N;
  // ---- stats phase (imp stays in registers) ----
  double sc = 0, sf = 0;
  for (int j = 0; j < 8; ++j){ int i = t + j*1024; sc += (double)curv[base+i]; sf += (double)fv[base+i]; }
  double Sc = blk_sum(sc, lds, t);
  double Sf = blk_sum(sf, lds, t);
  double mc = Sc/8192.0, mf = Sf/8192.0;
  double vc = 0, vf = 0;
  for (int j = 0; j < 8; ++j){ int i = t + j*1024;
    double d1 = (double)curv[base+i] - mc; vc += d1*d1;
    double d2 = (double)fv[base+i]  - mf; vf += d2*d2; }
  double Vc = blk_sum(vc, lds, t);
  double Vf = blk_sum(vf, lds, t);
  float mcf = (float)mc, mff = (float)mf;
  float dc = __fadd_rn((float)sqrt(Vc/8191.0), 1e-8f);
  float df = __fadd_rn((float)sqrt(Vf/8191.0), 1e-8f);
  // ---- topk phase ----
  #pragma unroll
  for (int j = 0; j < 2; ++j) hist[t + j*1024] = 0;
  if (t == 0) scal[3] = 0;
  __syncthreads();
  for (int j = 0; j < 8; ++j){
    int i = t + j*1024;
    float zc = fsubr(curv[base+i], mcf) / dc;
    float zf = fsubr(fv[base+i],  mff) / df;
    float impv = __fadd_rn(zc, __fmul_rn(0.5f, zf));
    unsigned u = ~okey(impv);          // ascending = descending importance
    dk[i] = u;
    int bin = (int)(u >> 16) - TBINBASE; bin = bin < 0 ? 0 : (bin > 2047 ? 2047 : bin);
    atomicAdd(&hist[bin], 1u);
  }
  __syncthreads();
  if (t < 64){
    unsigned s = 0;
    for (int k2 = 0; k2 < 32; ++k2) s += hist[t*32 + ((k2 + t) & 31)];
    unsigned p = s;
    for (int off = 1; off < 64; off <<= 1){ unsigned v = (unsigned)__shfl_up((int)p, off); if (t >= off) p += v; }
    int excl = (int)(p - s);
    if (excl < 1024 && (int)p >= 1024){ scal[0] = t; scal[1] = excl; }
  }
  __syncthreads();
  {
    int g = scal[0];
    if (t < 32){
      unsigned s = hist[g*32 + t];
      unsigned p = s;
      for (int off = 1; off < 32; off <<= 1){ unsigned v = (unsigned)__shfl_up((int)p, off); if (t >= off) p += v; }
      int before = scal[1] + (int)(p - s);
      if (before < 1024 && scal[1] + (int)p >= 1024) scal[2] = g*32 + t;
    }
  }
  __syncthreads();
  int B1 = scal[2];
  unsigned limit = (B1 >= 2047) ? 0xFFFFFFFFu : ((unsigned)(TBINBASE + B1 + 1) << 16);
  for (int j = 0; j < 8; ++j){
    int i = t + j*1024;
    unsigned u = dk[i];
    if (u < limit){
      int p = atomicAdd(&scal[3], 1);
      if (p < 2048) win[p] = ((unsigned long long)u << 13) | (unsigned)i;
    }
  }
  __syncthreads();
  int m = scal[3]; if (m > 2048) m = 2048;
  unsigned fk2 = *farkey;
  float rmax = (fk2 & 0x80000000u) ? __uint_as_float(fk2 & 0x7FFFFFFFu) : __uint_as_float(~fk2);
  const float far = __fadd_rn(rmax, 1.0f);
  for (int e = t; e < m; e += 1024){
    unsigned long long me = win[e];
    int rk = 0;
    for (int j2 = 0; j2 < m; ++j2) rk += (win[j2] < me) ? 1 : 0;
    if (rk < 1024){
      int idx = (int)(me & 0x1FFFull);
      merged[b*2048 + rk] = idx;
      mxyz[base + idx] = make_float4(far, far, far, 0.0f);
    }
  }
}

// ---------------- FPS (bit-exact fp32 chain), 1 block per batch — R6 structure + finalize tail
#define DPP_MAX64(CTRL) { \
    int nlo = __builtin_amdgcn_update_dpp(0, klo, (CTRL), 0xf, 0xf, true); \
    int nhi = __builtin_amdgcn_update_dpp(0, khi, (CTRL), 0xf, 0xf, true); \
    unsigned long long nk = ((unsigned long long)(unsigned)nhi << 32) | (unsigned)nlo; \
    unsigned long long ck = ((unsigned long long)(unsigned)khi << 32) | (unsigned)klo; \
    if (nk > ck){ klo = nlo; khi = nhi; } \
  }

__global__ __launch_bounds__(512, 2) void fps_kernel(const float4* __restrict__ mxyz, int* __restrict__ merged,
                                                     const float* __restrict__ xyz, float* __restrict__ out){
  extern __shared__ float4 stab[];            // 8192 float4 = 128 KB dynamic LDS
  __shared__ unsigned long long wkey[2][8];
  const int t = threadIdx.x;
  const int b = blockIdx.x;
  const int base = b * N;
  float px[16], py[16], pz[16], md[16];
  #pragma unroll
  for (int j = 0; j < 16; ++j){
    int i = t + j*512;
    float4 p = mxyz[base + i];
    px[j] = p.x; py[j] = p.y; pz[j] = p.z; md[j] = 1e10f;
    stab[i] = p;
  }
  if (t == 0) merged[b*2048 + 1024] = 0;      // first fps output is index 0
  __syncthreads();
  float4 w0 = stab[0];
  float lx = w0.x, ly = w0.y, lz = w0.z;
  for (int it = 0; it < 1023; ++it){
    float bestv = -1.0f; unsigned blow = 0u;
    #pragma unroll
    for (int j = 0; j < 16; ++j){
      float dx = fsubr(px[j], lx), dy = fsubr(py[j], ly), dz = fsubr(pz[j], lz);
      float d = __fadd_rn(__fadd_rn(__fmul_rn(dx,dx), __fmul_rn(dy,dy)), __fmul_rn(dz,dz));
      float nm = fminf(md[j], d);
      md[j] = nm;
      if (nm > bestv){ bestv = nm; blow = 8191u - (unsigned)(t + (j<<9)); }  // first-j kept on tie = smallest orig idx
    }
    unsigned long long key = ((unsigned long long)__float_as_uint(bestv) << 13) | (unsigned long long)blow;
    int klo = (int)(unsigned)(key & 0xFFFFFFFFull);
    int khi = (int)(unsigned)(key >> 32);
    DPP_MAX64(0x111)   // row_shr:1
    DPP_MAX64(0x112)   // row_shr:2
    DPP_MAX64(0x114)   // row_shr:4
    DPP_MAX64(0x118)   // row_shr:8
    DPP_MAX64(0x142)   // row_bcast:15
    DPP_MAX64(0x143)   // row_bcast:31  -> lane 63 holds wave max
    if ((t & 63) == 63)
      wkey[it & 1][t >> 6] = ((unsigned long long)(unsigned)khi << 32) | (unsigned)klo;
    __syncthreads();
    const unsigned long long* wk = wkey[it & 1];
    unsigned long long k = wk[0];
    #pragma unroll
    for (int i2 = 1; i2 < 8; ++i2){ unsigned long long o = wk[i2]; if (o > k) k = o; }
    const int idx = 8191 - (int)(k & 0x1FFFull);
    if (t == 0) merged[b*2048 + 1024 + it + 1] = idx;
    float4 wv = stab[idx];                    // uniform idx -> broadcast ds_read_b128
    lx = wv.x; ly = wv.y; lz = wv.z;
  }
  // ---- finalize tail: this batch's 2048 outputs (coords + idx-as-float) ----
  __threadfence_block();
  __syncthreads();
  for (int e = t; e < 2048; e += 512){
    int gi = b*2048 + e;
    int idx = merged[gi];
    out[12288 + gi] = (float)idx;
    const float* p = xyz + (size_t)(base + idx)*3;
    out[gi*3+0] = p[0]; out[gi*3+1] = p[1]; out[gi*3+2] = p[2];
  }
}

extern "C" void kernel_launch(void* const* d_in, const int* in_sizes, int n_in,
                              void* d_out, int out_size, void* d_ws, size_t ws_size,
                              hipStream_t stream){
  const float* xyz  = (const float*)d_in[0];
  const float* feat = (const float*)d_in[1];
  const float* w1   = (const float*)d_in[2];
  const float* b1   = (const float*)d_in[3];
  const float* w2   = (const float*)d_in[4];
  const float* b2   = (const float*)d_in[5];
  float* out = (float*)d_out;
  char* ws = (char*)d_ws;
  float*    Q      = (float*)   (ws);                  // 16384*128 f32 = 8 MB
  int*      cand   = (int*)     (ws + 8388608);        // 16384*64  i32 = 4 MB
  float*    xs     = (float*)   (ws + 12582912);
  float*    ysv    = (float*)   (ws + 12648448);
  float*    zsv    = (float*)   (ws + 12713984);
  float*    sq     = (float*)   (ws + 12779520);
  float*    curv   = (float*)   (ws + 12845056);
  float*    fv     = (float*)   (ws + 12910592);
  int*      merged = (int*)     (ws + 13041664);       // 4096 i32
  unsigned* farkey = (unsigned*)(ws + 13058048);       // 1 u32 (okey-encoded global max)
  float4*   mxyz   = (float4*)  (ws + 13058112);       // 16384 float4 = 256 KB (16B aligned)

  hipMemsetAsync(farkey, 0, 4, stream);
  aux_kernel<<<64, 256, 0, stream>>>(xyz, xs, ysv, zsv, sq, mxyz, farkey);
  q_kernel<<<1024, 128, 0, stream>>>(xyz, feat, w1, Q);
  knn_kernel<<<512, 512, 0, stream>>>(xs, ysv, zsv, sq, cand);
  score_kernel<<<4096, 256, 0, stream>>>(xyz, feat, Q, b1, w2, b2, cand, curv, fv);
  stats_topk_kernel<<<2, 1024, 0, stream>>>(curv, fv, merged, mxyz, farkey);
  fps_kernel<<<2, 512, 131072, stream>>>(mxyz, merged, xyz, out);
}

// Round 14
// 1605.518 us; speedup vs baseline: 2.6569x; 2.6569x over previous
//
#include <hip/hip_runtime.h>
#include <hip/hip_bf16.h>
#include <math.h>

#define N 8192
#define BATCH 2
#define NROWS (BATCH*N)

typedef float v2f __attribute__((ext_vector_type(2)));

static __device__ __forceinline__ float fsubr(float a, float b){ return __fadd_rn(a, -b); }
static __device__ __forceinline__ unsigned okey(float f){
  unsigned u = __float_as_uint(f);
  return (u & 0x80000000u) ? ~u : (u | 0x80000000u);
}

// ---------------- aux: transpose xyz + |p|^2 + masked-coord image + global max (okey atomicMax)
__global__ void aux_kernel(const float* __restrict__ xyz, float* __restrict__ xs, float* __restrict__ ys,
                           float* __restrict__ zs, float* __restrict__ sq, float4* __restrict__ mxyz,
                           unsigned* __restrict__ farkey){
  __shared__ unsigned lm[4];
  const int t = threadIdx.x;
  int i = blockIdx.x*256 + t;
  float m = -1e30f;
  if (i < NROWS){
    float x = xyz[i*3+0], y = xyz[i*3+1], z = xyz[i*3+2];
    xs[i]=x; ys[i]=y; zs[i]=z;
    sq[i] = __fadd_rn(__fadd_rn(__fmul_rn(x,x),__fmul_rn(y,y)),__fmul_rn(z,z));
    mxyz[i] = make_float4(x, y, z, 0.0f);
    m = fmaxf(fmaxf(x, y), z);
  }
  #pragma unroll
  for (int off = 32; off; off >>= 1) m = fmaxf(m, __shfl_down(m, off));
  if ((t & 63) == 0) lm[t >> 6] = okey(m);
  __syncthreads();
  if (t == 0){
    unsigned k = lm[0];
    k = k > lm[1] ? k : lm[1];
    k = k > lm[2] ? k : lm[2];
    k = k > lm[3] ? k : lm[3];
    atomicMax(farkey, k);
  }
}

// ---------------- Q = xyz @ w1[:3] + feat @ w1[3:]  (per global row, 128 cols)
__global__ __launch_bounds__(128) void q_kernel(const float* __restrict__ xyz, const float* __restrict__ feat,
                                                const float* __restrict__ w1, float* __restrict__ Q){
  __shared__ float sx[16][3];
  __shared__ float sf[16][64];
  const int t = threadIdx.x;
  const int row0 = blockIdx.x * 16;
  for (int j = t; j < 1024; j += 128) sf[j>>6][j&63] = feat[(size_t)row0*64 + j];
  if (t < 48) sx[t/3][t%3] = xyz[(size_t)row0*3 + t];
  __syncthreads();
  float acc[16];
  #pragma unroll
  for (int r = 0; r < 16; ++r) acc[r] = 0.0f;
  for (int c = 0; c < 3; ++c){
    float wv = w1[c*128 + t];
    #pragma unroll
    for (int r = 0; r < 16; ++r) acc[r] = fmaf(sx[r][c], wv, acc[r]);
  }
  for (int c = 0; c < 64; ++c){
    float wv = w1[(3+c)*128 + t];
    #pragma unroll
    for (int r = 0; r < 16; ++r) acc[r] = fmaf(sf[r][c], wv, acc[r]);
  }
  #pragma unroll
  for (int r = 0; r < 16; ++r) Q[(size_t)(row0+r)*128 + t] = acc[r];
}

// ---------------- KNN: per row, exact 65 smallest (d2, idx), drop rank0 (self), store 64 cand
// R12 version (measured best): fine histogram binning (bin = clamp((u>>16)-0xBA00, 0, 2047),
// monotone in u) -> distributed LDS atomics + tiny cutoff set (m ~= 65-95) for the exact
// rank scan. R13's bisection-select regressed 6x (single-counter atomics + unbounded m).
#define BINBASE 0xBA00
__global__ __launch_bounds__(512) void knn_kernel(const float* __restrict__ xs, const float* __restrict__ ys,
                                                  const float* __restrict__ zs, const float* __restrict__ sq,
                                                  int* __restrict__ cand){
#pragma clang fp contract(off)
  __shared__ unsigned fk[N];
  __shared__ unsigned hist[2048];
  __shared__ unsigned long long win[1024];
  __shared__ int scal[8];
  const int t = threadIdx.x;
  const int base_row = blockIdx.x * 32;           // 512 blocks x 32 rows
  const int b = base_row >> 13;
  const int n0 = base_row & (N-1);
  const int pbase = b * N;
  v2f px[8], py[8], pz[8], ps[8];
  #pragma unroll
  for (int k = 0; k < 8; ++k){
    int i0 = t + (2*k)*512, i1 = t + (2*k+1)*512;
    px[k].x = xs[pbase+i0]; px[k].y = xs[pbase+i1];
    py[k].x = ys[pbase+i0]; py[k].y = ys[pbase+i1];
    pz[k].x = zs[pbase+i0]; pz[k].y = zs[pbase+i1];
    ps[k].x = sq[pbase+i0]; ps[k].y = sq[pbase+i1];
  }
  for (int r = 0; r < 32; ++r){
    const int n = n0 + r;
    const float qx = xs[pbase+n], qy = ys[pbase+n], qz = zs[pbase+n], qs = sq[pbase+n];
    #pragma unroll
    for (int j = 0; j < 4; ++j) hist[t + j*512] = 0;
    __syncthreads();
    #pragma unroll
    for (int k = 0; k < 8; ++k){
      v2f dot = px[k]*qx + py[k]*qy + pz[k]*qz;       // ((mul+mul)+mul), rn, packable
      v2f dd  = (qs + ps[k]) - 2.0f*dot;              // 2*dot exact; one rounding on sub
      unsigned u0 = okey(dd.x), u1 = okey(dd.y);
      fk[t + (2*k)*512] = u0;
      fk[t + (2*k+1)*512] = u1;
      int bin0 = (int)(u0 >> 16) - BINBASE; bin0 = bin0 < 0 ? 0 : (bin0 > 2047 ? 2047 : bin0);
      int bin1 = (int)(u1 >> 16) - BINBASE; bin1 = bin1 < 0 ? 0 : (bin1 > 2047 ? 2047 : bin1);
      atomicAdd(&hist[bin0], 1u);
      atomicAdd(&hist[bin1], 1u);
    }
    __syncthreads();
    if (t < 64){
      unsigned s = 0;
      for (int k2 = 0; k2 < 32; ++k2) s += hist[t*32 + ((k2 + t) & 31)];   // rotated: conflict-free
      unsigned p = s;
      for (int off = 1; off < 64; off <<= 1){ unsigned v = (unsigned)__shfl_up((int)p, off); if (t >= off) p += v; }
      int excl = (int)(p - s);
      if (excl < 65 && (int)p >= 65){ scal[0] = t; scal[1] = excl; }
    }
    __syncthreads();
    {
      int g = scal[0];
      if (t < 32){
        unsigned s = hist[g*32 + t];
        unsigned p = s;
        for (int off = 1; off < 32; off <<= 1){ unsigned v = (unsigned)__shfl_up((int)p, off); if (t >= off) p += v; }
        int before = scal[1] + (int)(p - s);
        if (before < 65 && scal[1] + (int)p >= 65) scal[2] = g*32 + t;
      }
    }
    if (t == 0) scal[3] = 0;
    __syncthreads();
    int B1 = scal[2];
    unsigned limit = (B1 >= 2047) ? 0xFFFFFFFFu : ((unsigned)(BINBASE + B1 + 1) << 16);
    #pragma unroll
    for (int j = 0; j < 16; ++j){
      int i = t + j*512;
      unsigned u = fk[i];
      if (u < limit){
        int p = atomicAdd(&scal[3], 1);
        if (p < 1024) win[p] = ((unsigned long long)u << 32) | (unsigned)i;
      }
    }
    __syncthreads();
    int m = scal[3]; if (m > 1024) m = 1024;
    for (int e = t; e < m; e += 512){
      unsigned long long me = win[e];
      int rk = 0;
      for (int j2 = 0; j2 < m; ++j2) rk += (win[j2] < me) ? 1 : 0;
      if (rk >= 1 && rk < 65) cand[(size_t)(pbase + n)*64 + (rk-1)] = (int)(me & 0xFFFFFFFFull);
    }
    __syncthreads();
  }
}

// ---------------- scores + top16 + covariance/eigen curvature + feat_var  (one wave per row)
__global__ __launch_bounds__(256) void score_kernel(const float* __restrict__ xyz, const float* __restrict__ feat,
                                                    const float* __restrict__ Q, const float* __restrict__ b1,
                                                    const float* __restrict__ w2, const float* __restrict__ b2,
                                                    const int* __restrict__ cand,
                                                    float* __restrict__ curv, float* __restrict__ fv){
  __shared__ float4 sb14[32], sw24[32];
  __shared__ int ssel[4][16];
  __shared__ float sdx[4][16], sdy[4][16], sdz[4][16], snrm[4][16];
  const int t = threadIdx.x;
  if (t < 32) sb14[t] = ((const float4*)b1)[t];
  else if (t < 64) sw24[t-32] = ((const float4*)w2)[t-32];
  __syncthreads();
  const int w = t >> 6, lane = t & 63;
  const int row = blockIdx.x*4 + w;               // global row
  const int b = row >> 13;
  const int pbase = b * N;
  const int n = row & (N-1);
  const int ck = cand[(size_t)row*64 + lane];
  const float4* Qn4 = (const float4*)(Q + (size_t)row * 128);
  const float4* Qc4 = (const float4*)(Q + (size_t)(pbase + ck) * 128);
  const float ks = 0.70710678118654752440f;
  float acc = 0.0f;
  for (int c = 0; c < 32; ++c){
    float4 qc = Qc4[c], qn = Qn4[c], bb = sb14[c], ww = sw24[c];
    float p0 = (qc.x - qn.x) + bb.x;
    float g0 = 0.5f * p0 * (1.0f + erff(p0 * ks));
    acc += g0 * ww.x;
    float p1 = (qc.y - qn.y) + bb.y;
    float g1 = 0.5f * p1 * (1.0f + erff(p1 * ks));
    acc += g1 * ww.y;
    float p2 = (qc.z - qn.z) + bb.z;
    float g2 = 0.5f * p2 * (1.0f + erff(p2 * ks));
    acc += g2 * ww.z;
    float p3 = (qc.w - qn.w) + bb.w;
    float g3 = 0.5f * p3 * (1.0f + erff(p3 * ks));
    acc += g3 * ww.w;
  }
  float score = acc + b2[0];
  unsigned key = okey(score);
  int rk = 0;
  for (int j = 0; j < 64; ++j){
    unsigned kj = (unsigned)__shfl((int)key, j);
    rk += (kj > key || (kj == key && j < lane)) ? 1 : 0;
  }
  float cx = xyz[(size_t)(pbase+ck)*3+0], cy = xyz[(size_t)(pbase+ck)*3+1], cz = xyz[(size_t)(pbase+ck)*3+2];
  float qxv = xyz[(size_t)(pbase+n)*3+0], qyv = xyz[(size_t)(pbase+n)*3+1], qzv = xyz[(size_t)(pbase+n)*3+2];
  if (rk < 16){
    ssel[w][rk] = ck;
    sdx[w][rk] = fsubr(cx, qxv);
    sdy[w][rk] = fsubr(cy, qyv);
    sdz[w][rk] = fsubr(cz, qzv);
  }
  __syncthreads();
  if (lane < 16){
    int si = ssel[w][lane];
    const float4* fc4 = (const float4*)(feat + (size_t)(pbase+si)*64);
    const float4* fn4 = (const float4*)(feat + (size_t)(pbase+n)*64);
    double s = 0.0;
    for (int c = 0; c < 16; ++c){
      float4 a = fc4[c], bq = fn4[c];
      float d0 = fsubr(a.x, bq.x); s += (double)d0 * (double)d0;
      float d1 = fsubr(a.y, bq.y); s += (double)d1 * (double)d1;
      float d2 = fsubr(a.z, bq.z); s += (double)d2 * (double)d2;
      float d3 = fsubr(a.w, bq.w); s += (double)d3 * (double)d3;
    }
    snrm[w][lane] = sqrtf((float)s);
  }
  __syncthreads();
  if (lane == 0){
    double cxx=0, cxy=0, cxz=0, cyy=0, cyz=0, czz=0;
    for (int k2 = 0; k2 < 16; ++k2){
      double dx = (double)sdx[w][k2], dy = (double)sdy[w][k2], dz = (double)sdz[w][k2];
      cxx += dx*dx; cxy += dx*dy; cxz += dx*dz; cyy += dy*dy; cyz += dy*dz; czz += dz*dz;
    }
    float fxx = (float)(cxx/16.0), fxy = (float)(cxy/16.0), fxz = (float)(cxz/16.0);
    float fyy = (float)(cyy/16.0), fyz = (float)(cyz/16.0), fzz = (float)(czz/16.0);
    double a = fxx, bbv = fyy, c = fzz, d = fxy, e = fyz, f = fxz;
    double p1 = d*d + f*f + e*e;
    double e0, e1, e2v;
    if (p1 == 0.0){ e0 = a; e1 = bbv; e2v = c; }
    else {
      double q = (a + bbv + c) / 3.0;
      double aa = a - q, bq = bbv - q, cc = c - q;
      double p2 = aa*aa + bq*bq + cc*cc + 2.0*p1;
      double p = sqrt(p2 / 6.0);
      double inv = 1.0 / p;
      double bxx = aa*inv, byy = bq*inv, bzz = cc*inv, bxy = d*inv, bxz = f*inv, byz = e*inv;
      double detB = bxx*(byy*bzz - byz*byz) - bxy*(bxy*bzz - byz*bxz) + bxz*(bxy*byz - byy*bxz);
      double rr = 0.5 * detB;
      rr = fmin(1.0, fmax(-1.0, rr));
      double phi = acos(rr) / 3.0;
      e0 = q + 2.0*p*cos(phi);
      e2v = q + 2.0*p*cos(phi + 2.0943951023931953);
      e1 = 3.0*q - e0 - e2v;
    }
    double s0 = fabs(e0), s1 = fabs(e1), s2d = fabs(e2v), tt;
    if (s0 < s1){ tt=s0; s0=s1; s1=tt; }
    if (s1 < s2d){ tt=s1; s1=s2d; s2d=tt; }
    if (s0 < s1){ tt=s0; s0=s1; s1=tt; }
    float sv0 = (float)s0, sv1 = (float)s1, sv2 = (float)s2d;
    float l2f = __fmul_rn(sv0,sv0), l1f = __fmul_rn(sv1,sv1), l0f = __fmul_rn(sv2,sv2);
    float den = __fadd_rn(__fadd_rn(__fadd_rn(l0f, l1f), l2f), 1e-8f);
    curv[row] = l0f / den;
    double fs = 0.0;
    for (int k2 = 0; k2 < 16; ++k2) fs += (double)snrm[w][k2];
    fv[row] = (float)(fs / 16.0);
  }
}

// ---------------- merged: per-batch znorm + importance (regs) -> top-1024 + masked-coord scatter
static __device__ __forceinline__ double blk_sum(double v, double* lds, int t){
  for (int off = 32; off; off >>= 1) v += __shfl_down(v, off);
  int w = t >> 6, lane = t & 63;
  if (lane == 0) lds[w] = v;
  __syncthreads();
  double r = (t < 16) ? lds[t] : 0.0;
  if (t < 64){ for (int off = 8; off; off >>= 1) r += __shfl_down(r, off); }
  if (t == 0) lds[0] = r;
  __syncthreads();
  double out = lds[0];
  __syncthreads();
  return out;
}

#define TBINBASE 0x3E00
__global__ __launch_bounds__(1024) void stats_topk_kernel(const float* __restrict__ curv, const float* __restrict__ fv,
                                                          int* __restrict__ merged, float4* __restrict__ mxyz,
                                                          const unsigned* __restrict__ farkey){
  __shared__ unsigned dk[N];
  __shared__ unsigned hist[2048];
  __shared__ unsigned long long win[2048];
  __shared__ int scal[8];
  __shared__ double lds[16];
  const int t = threadIdx.x;
  const int b = blockIdx.x;
  const int base = b * N;
  // ---- stats phase (imp stays in registers) ----
  double sc = 0, sf = 0;
  for (int j = 0; j < 8; ++j){ int i = t + j*1024; sc += (double)curv[base+i]; sf += (double)fv[base+i]; }
  double Sc = blk_sum(sc, lds, t);
  double Sf = blk_sum(sf, lds, t);
  double mc = Sc/8192.0, mf = Sf/8192.0;
  double vc = 0, vf = 0;
  for (int j = 0; j < 8; ++j){ int i = t + j*1024;
    double d1 = (double)curv[base+i] - mc; vc += d1*d1;
    double d2 = (double)fv[base+i]  - mf; vf += d2*d2; }
  double Vc = blk_sum(vc, lds, t);
  double Vf = blk_sum(vf, lds, t);
  float mcf = (float)mc, mff = (float)mf;
  float dc = __fadd_rn((float)sqrt(Vc/8191.0), 1e-8f);
  float df = __fadd_rn((float)sqrt(Vf/8191.0), 1e-8f);
  // ---- topk phase ----
  #pragma unroll
  for (int j = 0; j < 2; ++j) hist[t + j*1024] = 0;
  if (t == 0) scal[3] = 0;
  __syncthreads();
  for (int j = 0; j < 8; ++j){
    int i = t + j*1024;
    float zc = fsubr(curv[base+i], mcf) / dc;
    float zf = fsubr(fv[base+i],  mff) / df;
    float impv = __fadd_rn(zc, __fmul_rn(0.5f, zf));
    unsigned u = ~okey(impv);          // ascending = descending importance
    dk[i] = u;
    int bin = (int)(u >> 16) - TBINBASE; bin = bin < 0 ? 0 : (bin > 2047 ? 2047 : bin);
    atomicAdd(&hist[bin], 1u);
  }
  __syncthreads();
  if (t < 64){
    unsigned s = 0;
    for (int k2 = 0; k2 < 32; ++k2) s += hist[t*32 + ((k2 + t) & 31)];
    unsigned p = s;
    for (int off = 1; off < 64; off <<= 1){ unsigned v = (unsigned)__shfl_up((int)p, off); if (t >= off) p += v; }
    int excl = (int)(p - s);
    if (excl < 1024 && (int)p >= 1024){ scal[0] = t; scal[1] = excl; }
  }
  __syncthreads();
  {
    int g = scal[0];
    if (t < 32){
      unsigned s = hist[g*32 + t];
      unsigned p = s;
      for (int off = 1; off < 32; off <<= 1){ unsigned v = (unsigned)__shfl_up((int)p, off); if (t >= off) p += v; }
      int before = scal[1] + (int)(p - s);
      if (before < 1024 && scal[1] + (int)p >= 1024) scal[2] = g*32 + t;
    }
  }
  __syncthreads();
  int B1 = scal[2];
  unsigned limit = (B1 >= 2047) ? 0xFFFFFFFFu : ((unsigned)(TBINBASE + B1 + 1) << 16);
  for (int j = 0; j < 8; ++j){
    int i = t + j*1024;
    unsigned u = dk[i];
    if (u < limit){
      int p = atomicAdd(&scal[3], 1);
      if (p < 2048) win[p] = ((unsigned long long)u << 13) | (unsigned)i;
    }
  }
  __syncthreads();
  int m = scal[3]; if (m > 2048) m = 2048;
  unsigned fk2 = *farkey;
  float rmax = (fk2 & 0x80000000u) ? __uint_as_float(fk2 & 0x7FFFFFFFu) : __uint_as_float(~fk2);
  const float far = __fadd_rn(rmax, 1.0f);
  for (int e = t; e < m; e += 1024){
    unsigned long long me = win[e];
    int rk = 0;
    for (int j2 = 0; j2 < m; ++j2) rk += (win[j2] < me) ? 1 : 0;
    if (rk < 1024){
      int idx = (int)(me & 0x1FFFull);
      merged[b*2048 + rk] = idx;
      mxyz[base + idx] = make_float4(far, far, far, 0.0f);
    }
  }
}

// ---------------- FPS (bit-exact fp32 chain), 1 block per batch — R6 structure + finalize tail
#define DPP_MAX64(CTRL) { \
    int nlo = __builtin_amdgcn_update_dpp(0, klo, (CTRL), 0xf, 0xf, true); \
    int nhi = __builtin_amdgcn_update_dpp(0, khi, (CTRL), 0xf, 0xf, true); \
    unsigned long long nk = ((unsigned long long)(unsigned)nhi << 32) | (unsigned)nlo; \
    unsigned long long ck = ((unsigned long long)(unsigned)khi << 32) | (unsigned)klo; \
    if (nk > ck){ klo = nlo; khi = nhi; } \
  }

__global__ __launch_bounds__(512, 2) void fps_kernel(const float4* __restrict__ mxyz, int* __restrict__ merged,
                                                     const float* __restrict__ xyz, float* __restrict__ out){
  extern __shared__ float4 stab[];            // 8192 float4 = 128 KB dynamic LDS
  __shared__ unsigned long long wkey[2][8];
  const int t = threadIdx.x;
  const int b = blockIdx.x;
  const int base = b * N;
  float px[16], py[16], pz[16], md[16];
  #pragma unroll
  for (int j = 0; j < 16; ++j){
    int i = t + j*512;
    float4 p = mxyz[base + i];
    px[j] = p.x; py[j] = p.y; pz[j] = p.z; md[j] = 1e10f;
    stab[i] = p;
  }
  if (t == 0) merged[b*2048 + 1024] = 0;      // first fps output is index 0
  __syncthreads();
  float4 w0 = stab[0];
  float lx = w0.x, ly = w0.y, lz = w0.z;
  for (int it = 0; it < 1023; ++it){
    float bestv = -1.0f; unsigned blow = 0u;
    #pragma unroll
    for (int j = 0; j < 16; ++j){
      float dx = fsubr(px[j], lx), dy = fsubr(py[j], ly), dz = fsubr(pz[j], lz);
      float d = __fadd_rn(__fadd_rn(__fmul_rn(dx,dx), __fmul_rn(dy,dy)), __fmul_rn(dz,dz));
      float nm = fminf(md[j], d);
      md[j] = nm;
      if (nm > bestv){ bestv = nm; blow = 8191u - (unsigned)(t + (j<<9)); }  // first-j kept on tie = smallest orig idx
    }
    unsigned long long key = ((unsigned long long)__float_as_uint(bestv) << 13) | (unsigned long long)blow;
    int klo = (int)(unsigned)(key & 0xFFFFFFFFull);
    int khi = (int)(unsigned)(key >> 32);
    DPP_MAX64(0x111)   // row_shr:1
    DPP_MAX64(0x112)   // row_shr:2
    DPP_MAX64(0x114)   // row_shr:4
    DPP_MAX64(0x118)   // row_shr:8
    DPP_MAX64(0x142)   // row_bcast:15
    DPP_MAX64(0x143)   // row_bcast:31  -> lane 63 holds wave max
    if ((t & 63) == 63)
      wkey[it & 1][t >> 6] = ((unsigned long long)(unsigned)khi << 32) | (unsigned)klo;
    __syncthreads();
    const unsigned long long* wk = wkey[it & 1];
    unsigned long long k = wk[0];
    #pragma unroll
    for (int i2 = 1; i2 < 8; ++i2){ unsigned long long o = wk[i2]; if (o > k) k = o; }
    const int idx = 8191 - (int)(k & 0x1FFFull);
    if (t == 0) merged[b*2048 + 1024 + it + 1] = idx;
    float4 wv = stab[idx];                    // uniform idx -> broadcast ds_read_b128
    lx = wv.x; ly = wv.y; lz = wv.z;
  }
  // ---- finalize tail: this batch's 2048 outputs (coords + idx-as-float) ----
  __threadfence_block();
  __syncthreads();
  for (int e = t; e < 2048; e += 512){
    int gi = b*2048 + e;
    int idx = merged[gi];
    out[12288 + gi] = (float)idx;
    const float* p = xyz + (size_t)(base + idx)*3;
    out[gi*3+0] = p[0]; out[gi*3+1] = p[1]; out[gi*3+2] = p[2];
  }
}

extern "C" void kernel_launch(void* const* d_in, const int* in_sizes, int n_in,
                              void* d_out, int out_size, void* d_ws, size_t ws_size,
                              hipStream_t stream){
  const float* xyz  = (const float*)d_in[0];
  const float* feat = (const float*)d_in[1];
  const float* w1   = (const float*)d_in[2];
  const float* b1   = (const float*)d_in[3];
  const float* w2   = (const float*)d_in[4];
  const float* b2   = (const float*)d_in[5];
  float* out = (float*)d_out;
  char* ws = (char*)d_ws;
  float*    Q      = (float*)   (ws);                  // 16384*128 f32 = 8 MB
  int*      cand   = (int*)     (ws + 8388608);        // 16384*64  i32 = 4 MB
  float*    xs     = (float*)   (ws + 12582912);
  float*    ysv    = (float*)   (ws + 12648448);
  float*    zsv    = (float*)   (ws + 12713984);
  float*    sq     = (float*)   (ws + 12779520);
  float*    curv   = (float*)   (ws + 12845056);
  float*    fv     = (float*)   (ws + 12910592);
  int*      merged = (int*)     (ws + 13041664);       // 4096 i32
  unsigned* farkey = (unsigned*)(ws + 13058048);       // 1 u32 (okey-encoded global max)
  float4*   mxyz   = (float4*)  (ws + 13058112);       // 16384 float4 = 256 KB (16B aligned)

  hipMemsetAsync(farkey, 0, 4, stream);
  aux_kernel<<<64, 256, 0, stream>>>(xyz, xs, ysv, zsv, sq, mxyz, farkey);
  q_kernel<<<1024, 128, 0, stream>>>(xyz, feat, w1, Q);
  knn_kernel<<<512, 512, 0, stream>>>(xs, ysv, zsv, sq, cand);
  score_kernel<<<4096, 256, 0, stream>>>(xyz, feat, Q, b1, w2, b2, cand, curv, fv);
  stats_topk_kernel<<<2, 1024, 0, stream>>>(curv, fv, merged, mxyz, farkey);
  fps_kernel<<<2, 512, 131072, stream>>>(mxyz, merged, xyz, out);
}